// Round 1
// baseline (765.464 us; speedup 1.0000x reference)
//
#include <hip/hip_runtime.h>
#include <cstdint>
#include <math.h>

// ---------------------------------------------------------------------------
// LlamaSelfAttentionBlock: rmsnorm -> QKV (rope-diag) -> causal attn -> +res
//                          -> rmsnorm -> w1+b1 -> silu(beta*gate)*lin -> w2+b2 -> +res
// All matmuls in fp16 MFMA (16x16x32), f32 accumulate. B=2,L=2048,E=2048,H=16,hd=128,F=4096.
// ---------------------------------------------------------------------------

typedef _Float16 f16;
typedef _Float16 f16x8 __attribute__((ext_vector_type(8)));
typedef _Float16 f16x4 __attribute__((ext_vector_type(4)));
typedef float    f32x4 __attribute__((ext_vector_type(4)));

#define MFMA_16x16x32(a, b, c) __builtin_amdgcn_mfma_f32_16x16x32_f16(a, b, c, 0, 0, 0)

// global -> LDS direct copy, 16B per lane. LDS dest must be wave-uniform base;
// HW writes base + lane*16 (guide §5). Swizzling is done on the GLOBAL source.
__device__ __forceinline__ void gload_lds16(const void* g, void* lds) {
  __builtin_amdgcn_global_load_lds(
      (__attribute__((address_space(1))) void*)(uintptr_t)g,
      (__attribute__((address_space(3))) void*)(unsigned)(uintptr_t)lds,
      16, 0, 0);
}

// ---------------------------------------------------------------------------
// f32 [K][N] -> fp16 [N][K] transpose+convert (32x32 LDS tile)
// ---------------------------------------------------------------------------
__global__ void convT_k(const float* __restrict__ W, f16* __restrict__ Wt,
                        int K, int N) {
  __shared__ float tile[32][33];
  const int n0 = blockIdx.x << 5, k0 = blockIdx.y << 5;
  const int t = threadIdx.x;
  const int r = t >> 3, c4 = (t & 7) << 2;
  const f32x4 v = *(const f32x4*)(W + (size_t)(k0 + r) * N + n0 + c4);
  tile[r][c4 + 0] = v[0]; tile[r][c4 + 1] = v[1];
  tile[r][c4 + 2] = v[2]; tile[r][c4 + 3] = v[3];
  __syncthreads();
  f16x4 o;
  o[0] = (f16)tile[c4 + 0][r]; o[1] = (f16)tile[c4 + 1][r];
  o[2] = (f16)tile[c4 + 2][r]; o[3] = (f16)tile[c4 + 3][r];
  *(f16x4*)(Wt + (size_t)(n0 + r) * K + k0 + c4) = o;
}

// ---------------------------------------------------------------------------
// rope diag table: D[l][d] = cos(l * 10000^(-2*(d/2)/128)), f32 [2048][128]
// ---------------------------------------------------------------------------
__global__ void rope_tab_k(float* __restrict__ Dt) {
  const int l = blockIdx.x, d = threadIdx.x;
  // theta = exp(-(d&~1) * ln(10000)/128)
  const float th = __expf(-0.0719557841f * (float)(d & ~1));
  Dt[(l << 7) + d] = cosf((float)l * th);
}

// ---------------------------------------------------------------------------
// RMSNorm row kernel: f32 [rows][2048] -> fp16, one block (256 thr) per row
// ---------------------------------------------------------------------------
__global__ void rmsnorm_k(const float* __restrict__ X, const float* __restrict__ G,
                          f16* __restrict__ H) {
  __shared__ float red[4];
  const int row = blockIdx.x, t = threadIdx.x;
  const float* xp = X + ((size_t)row << 11) + (t << 3);
  const f32x4 v0 = *(const f32x4*)xp;
  const f32x4 v1 = *(const f32x4*)(xp + 4);
  float ss = v0[0]*v0[0] + v0[1]*v0[1] + v0[2]*v0[2] + v0[3]*v0[3]
           + v1[0]*v1[0] + v1[1]*v1[1] + v1[2]*v1[2] + v1[3]*v1[3];
#pragma unroll
  for (int m = 1; m < 64; m <<= 1) ss += __shfl_xor(ss, m);
  if ((t & 63) == 0) red[t >> 6] = ss;
  __syncthreads();
  const float tot = red[0] + red[1] + red[2] + red[3];
  const float rs = rsqrtf(tot * (1.f / 2048.f) + 1e-6f);
  const float* gp = G + (t << 3);
  const f32x4 g0 = *(const f32x4*)gp, g1 = *(const f32x4*)(gp + 4);
  f16x8 o;
  o[0] = (f16)(v0[0]*rs*g0[0]); o[1] = (f16)(v0[1]*rs*g0[1]);
  o[2] = (f16)(v0[2]*rs*g0[2]); o[3] = (f16)(v0[3]*rs*g0[3]);
  o[4] = (f16)(v1[0]*rs*g1[0]); o[5] = (f16)(v1[1]*rs*g1[1]);
  o[6] = (f16)(v1[2]*rs*g1[2]); o[7] = (f16)(v1[3]*rs*g1[3]);
  *(f16x8*)(H + ((size_t)row << 11) + (t << 3)) = o;
}

// ---------------------------------------------------------------------------
// per-head V transpose: V [B*L][E] -> Vt [B*H][128][2048]  (fp16)
// ---------------------------------------------------------------------------
__global__ void vtrans_k(const f16* __restrict__ V, f16* __restrict__ Vt) {
  __shared__ f16 tile[32][36];
  const int l0 = blockIdx.x << 5, d0 = blockIdx.y << 5, bh = blockIdx.z;
  const int b = bh >> 4, h = bh & 15;
  const int t = threadIdx.x;
  const int r = t >> 3, c4 = (t & 7) << 2;
  const f16x4 v = *(const f16x4*)(V + (size_t)((b << 11) + l0 + r) * 2048 + (h << 7) + d0 + c4);
  tile[r][c4 + 0] = v[0]; tile[r][c4 + 1] = v[1];
  tile[r][c4 + 2] = v[2]; tile[r][c4 + 3] = v[3];
  __syncthreads();
  f16x4 o;
  o[0] = tile[c4 + 0][r]; o[1] = tile[c4 + 1][r];
  o[2] = tile[c4 + 2][r]; o[3] = tile[c4 + 3][r];
  *(f16x4*)(Vt + (size_t)((bh << 7) + d0 + r) * 2048 + l0 + c4) = o;
}

// ---------------------------------------------------------------------------
// fp16 GEMM, 128x128 tile, BK=64, 4 waves (2x2), 16x16x32 MFMA.
// A [M][K] fp16 row-major, Bt [N][K] fp16 (pre-transposed). XOR-swizzled LDS
// (chunk ^= row&7 on 16B chunks) staged via global_load_lds with pre-swizzled
// global source (rule #21).
// EPI: 0=rope*scale->f16  1=plain->f16  2=+bias->f16  3=+bias,silu(beta)->f16
//      4=+bias,*auxh->f16  5=+bias,+auxf residual ->f32
// ---------------------------------------------------------------------------
template <int EPI>
__launch_bounds__(256, 2)
__global__ void gemm_k(const f16* __restrict__ A, const f16* __restrict__ Bt,
                       void* __restrict__ Cout, int M, int N, int K,
                       const float* __restrict__ bias,
                       const float* __restrict__ auxf,
                       const f16* __restrict__ auxh,
                       const float* __restrict__ betap,
                       float scale) {
  __shared__ alignas(16) f16 As[128 * 64];
  __shared__ alignas(16) f16 Bs[128 * 64];
  const int t = threadIdx.x;
  const int lane = t & 63;
  const int w = t >> 6;
  const int wm = w >> 1, wn = w & 1;
  const int bm = blockIdx.y << 7;
  const int bn = blockIdx.x << 7;
  const int lh = lane & 15, lq = lane >> 4;

  f32x4 acc[4][4] = {};

  for (int k0 = 0; k0 < K; k0 += 64) {
    __syncthreads();  // previous iter's readers done before overwrite
#pragma unroll
    for (int i = 0; i < 4; ++i) {
      const int idx = i * 256 + (w << 6) + lane;  // chunk 0..1023
      const int row = idx >> 3, c = idx & 7;
      const int cs = (c ^ (row & 7)) << 3;  // inverse-swizzled source (halves)
      gload_lds16(A + (size_t)(bm + row) * K + k0 + cs,
                  &As[(i * 256 + (w << 6)) << 3]);
      gload_lds16(Bt + (size_t)(bn + row) * K + k0 + cs,
                  &Bs[(i * 256 + (w << 6)) << 3]);
    }
    asm volatile("s_waitcnt vmcnt(0)" ::: "memory");
    __syncthreads();
#pragma unroll
    for (int kk = 0; kk < 2; ++kk) {
      f16x8 af[4], bf[4];
#pragma unroll
      for (int mi = 0; mi < 4; ++mi) {
        const int r = (wm << 6) + (mi << 4) + lh;
        af[mi] = *(const f16x8*)&As[(r << 6) + ((((kk << 2) + lq) ^ (r & 7)) << 3)];
      }
#pragma unroll
      for (int ni = 0; ni < 4; ++ni) {
        const int r = (wn << 6) + (ni << 4) + lh;
        bf[ni] = *(const f16x8*)&Bs[(r << 6) + ((((kk << 2) + lq) ^ (r & 7)) << 3)];
      }
#pragma unroll
      for (int mi = 0; mi < 4; ++mi)
#pragma unroll
        for (int ni = 0; ni < 4; ++ni)
          acc[mi][ni] = MFMA_16x16x32(af[mi], bf[ni], acc[mi][ni]);
    }
  }

  const float be = (EPI == 3) ? betap[0] : 0.f;
#pragma unroll
  for (int mi = 0; mi < 4; ++mi) {
#pragma unroll
    for (int ni = 0; ni < 4; ++ni) {
#pragma unroll
      for (int r = 0; r < 4; ++r) {
        const int grow = bm + (wm << 6) + (mi << 4) + (lq << 2) + r;
        const int gcol = bn + (wn << 6) + (ni << 4) + lh;
        float v = acc[mi][ni][r];
        if (EPI >= 2) v += bias[gcol];
        const size_t off = (size_t)grow * N + gcol;
        if (EPI == 0) {
          v *= scale * auxf[((grow & 2047) << 7) + (gcol & 127)];
          ((f16*)Cout)[off] = (f16)v;
        } else if (EPI == 1 || EPI == 2) {
          ((f16*)Cout)[off] = (f16)v;
        } else if (EPI == 3) {
          ((f16*)Cout)[off] = (f16)(v / (1.f + __expf(-be * v)));
        } else if (EPI == 4) {
          ((f16*)Cout)[off] = (f16)(v * (float)auxh[off]);
        } else {
          ((float*)Cout)[off] = v + auxf[off];
        }
      }
    }
  }
}

// ---------------------------------------------------------------------------
// Causal flash attention. grid (L/128, B*H), 256 thr (4 waves x 32 q-rows).
// Q pre-scaled by rope*1/sqrt(hd); K pre-scaled by rope. KV tile = 64.
// K staged [kv][128] swizzled; V staged from per-head-transposed Vt as
// [d][kv] swizzled; P round-trips through padded per-wave LDS.
// ---------------------------------------------------------------------------
__launch_bounds__(256, 2)
__global__ void attn_k(const f16* __restrict__ Q, const f16* __restrict__ Kb,
                       const f16* __restrict__ Vt, const float* __restrict__ Xres,
                       float* __restrict__ X2) {
  constexpr int L = 2048, E = 2048, HD = 128;
  __shared__ alignas(16) f16 Ks[64 * 128];
  __shared__ alignas(16) f16 Vs[128 * 64];
  __shared__ alignas(16) f16 Ps[4][32 * 72];

  const int t = threadIdx.x, lane = t & 63, w = t >> 6;
  const int q0 = blockIdx.x << 7;
  const int bh = blockIdx.y;
  const int b = bh >> 4, h = bh & 15;
  const int lh = lane & 15, lq = lane >> 4;
  const int wrow0 = q0 + (w << 5);

  // Q fragments in registers: [mi][kq], row = wrow0+mi*16+lh, k = kq*32+lq*8
  f16x8 qf[2][4];
#pragma unroll
  for (int mi = 0; mi < 2; ++mi) {
    const f16* qrow = Q + (size_t)(b * L + wrow0 + (mi << 4) + lh) * E + h * HD;
#pragma unroll
    for (int kq = 0; kq < 4; ++kq)
      qf[mi][kq] = *(const f16x8*)(qrow + (kq << 5) + (lq << 3));
  }

  f32x4 oacc[2][8] = {};
  float mrun[2][4], lrun[2][4];
#pragma unroll
  for (int mi = 0; mi < 2; ++mi)
#pragma unroll
    for (int r = 0; r < 4; ++r) { mrun[mi][r] = -1e30f; lrun[mi][r] = 0.f; }

  const int nkv = q0 + 128;
  for (int kv0 = 0; kv0 < nkv; kv0 += 64) {
    __syncthreads();
#pragma unroll
    for (int i = 0; i < 4; ++i) {
      const int idx = i * 256 + (w << 6) + lane;
      {  // K tile: 64 rows x 128 halves, 16 chunks/row
        const int row = idx >> 4, c = idx & 15;
        gload_lds16(Kb + (size_t)(b * L + kv0 + row) * E + h * HD + ((c ^ (row & 7)) << 3),
                    &Ks[(i * 256 + (w << 6)) << 3]);
      }
      {  // V tile (transposed): 128 rows x 64 halves, 8 chunks/row
        const int row = idx >> 3, c = idx & 7;
        gload_lds16(Vt + ((size_t)bh * HD + row) * L + kv0 + ((c ^ (row & 7)) << 3),
                    &Vs[(i * 256 + (w << 6)) << 3]);
      }
    }
    asm volatile("s_waitcnt vmcnt(0)" ::: "memory");
    __syncthreads();

    if (kv0 <= wrow0 + 31) {  // wave has at least one unmasked column
      // S = Q K^T  (32 q-rows x 64 kv)
      f32x4 sacc[2][4] = {};
#pragma unroll
      for (int kq = 0; kq < 4; ++kq) {
        f16x8 kf[4];
#pragma unroll
        for (int ni = 0; ni < 4; ++ni) {
          const int r = (ni << 4) + lh;
          kf[ni] = *(const f16x8*)&Ks[(r << 7) + ((((kq << 2) + lq) ^ (r & 7)) << 3)];
        }
#pragma unroll
        for (int mi = 0; mi < 2; ++mi)
#pragma unroll
          for (int ni = 0; ni < 4; ++ni)
            sacc[mi][ni] = MFMA_16x16x32(qf[mi][kq], kf[ni], sacc[mi][ni]);
      }
      if (kv0 + 63 > wrow0) {  // diagonal overlap -> causal mask
#pragma unroll
        for (int mi = 0; mi < 2; ++mi)
#pragma unroll
          for (int ni = 0; ni < 4; ++ni)
#pragma unroll
            for (int r = 0; r < 4; ++r) {
              const int qr = wrow0 + (mi << 4) + (lq << 2) + r;
              const int kv = kv0 + (ni << 4) + lh;
              if (kv > qr) sacc[mi][ni][r] = -1e30f;
            }
      }
      // online softmax: row = (mi, lq, r); reduce across 16 lanes
      float scl[2][4], rsum[2][4];
#pragma unroll
      for (int mi = 0; mi < 2; ++mi)
#pragma unroll
        for (int r = 0; r < 4; ++r) {
          float v = fmaxf(fmaxf(sacc[mi][0][r], sacc[mi][1][r]),
                          fmaxf(sacc[mi][2][r], sacc[mi][3][r]));
          v = fmaxf(v, __shfl_xor(v, 1));
          v = fmaxf(v, __shfl_xor(v, 2));
          v = fmaxf(v, __shfl_xor(v, 4));
          v = fmaxf(v, __shfl_xor(v, 8));
          const float mnew = fmaxf(mrun[mi][r], v);
          scl[mi][r] = __expf(mrun[mi][r] - mnew);
          mrun[mi][r] = mnew;
          rsum[mi][r] = 0.f;
        }
#pragma unroll
      for (int mi = 0; mi < 2; ++mi)
#pragma unroll
        for (int ni = 0; ni < 4; ++ni)
#pragma unroll
          for (int r = 0; r < 4; ++r) {
            const float p = __expf(sacc[mi][ni][r] - mrun[mi][r]);
            rsum[mi][r] += p;
            Ps[w][((mi << 4) + (lq << 2) + r) * 72 + (ni << 4) + lh] = (f16)p;
          }
#pragma unroll
      for (int mi = 0; mi < 2; ++mi)
#pragma unroll
        for (int r = 0; r < 4; ++r) {
          float s = rsum[mi][r];
          s += __shfl_xor(s, 1);
          s += __shfl_xor(s, 2);
          s += __shfl_xor(s, 4);
          s += __shfl_xor(s, 8);
          lrun[mi][r] = lrun[mi][r] * scl[mi][r] + s;
        }
#pragma unroll
      for (int mi = 0; mi < 2; ++mi)
#pragma unroll
        for (int nd = 0; nd < 8; ++nd)
#pragma unroll
          for (int r = 0; r < 4; ++r) oacc[mi][nd][r] *= scl[mi][r];
      // O += P V  (per-wave private LDS; compiler orders ds_write->ds_read)
#pragma unroll
      for (int kp = 0; kp < 2; ++kp) {
        f16x8 pf[2];
#pragma unroll
        for (int mi = 0; mi < 2; ++mi)
          pf[mi] = *(const f16x8*)&Ps[w][((mi << 4) + lh) * 72 + (kp << 5) + (lq << 3)];
#pragma unroll
        for (int nd = 0; nd < 8; ++nd) {
          const int r = (nd << 4) + lh;
          const f16x8 vf = *(const f16x8*)&Vs[(r << 6) + ((((kp << 2) + lq) ^ (r & 7)) << 3)];
#pragma unroll
          for (int mi = 0; mi < 2; ++mi)
            oacc[mi][nd] = MFMA_16x16x32(pf[mi], vf, oacc[mi][nd]);
        }
      }
    }
  }
  // write O/l + residual
#pragma unroll
  for (int mi = 0; mi < 2; ++mi)
#pragma unroll
    for (int nd = 0; nd < 8; ++nd)
#pragma unroll
      for (int r = 0; r < 4; ++r) {
        const int qr = wrow0 + (mi << 4) + (lq << 2) + r;
        const size_t off = (size_t)(b * L + qr) * E + h * HD + (nd << 4) + lh;
        X2[off] = oacc[mi][nd][r] / lrun[mi][r] + Xres[off];
      }
}

// ---------------------------------------------------------------------------
extern "C" void kernel_launch(void* const* d_in, const int* in_sizes, int n_in,
                              void* d_out, int out_size, void* d_ws, size_t ws_size,
                              hipStream_t stream) {
  const float* x    = (const float*)d_in[0];
  const float* g    = (const float*)d_in[1];
  const float* wq   = (const float*)d_in[2];
  const float* wk   = (const float*)d_in[3];
  const float* wv   = (const float*)d_in[4];
  const float* w1   = (const float*)d_in[5];
  const float* b1   = (const float*)d_in[6];
  const float* wgp  = (const float*)d_in[7];
  const float* bg   = (const float*)d_in[8];
  const float* wl   = (const float*)d_in[9];
  const float* bl   = (const float*)d_in[10];
  const float* beta = (const float*)d_in[11];
  const float* w2   = (const float*)d_in[12];
  const float* b2   = (const float*)d_in[13];

  constexpr size_t MB = 1ull << 20;
  char* ws = (char*)d_ws;
  // JIT weight-transpose scratch (largest weight = 32MB fp16), reused per GEMM
  f16*   wT   = (f16*)(ws + 0 * MB);      // 0..32
  float* Dt   = (float*)(ws + 32 * MB);   // 32..33
  f16*   hbuf = (f16*)(ws + 33 * MB);     // 33..49   (h, then h2)
  f16*   qbuf = (f16*)(ws + 49 * MB);     // 49..65
  f16*   kbuf = (f16*)(ws + 65 * MB);     // 65..81
  f16*   vbuf = (f16*)(ws + 81 * MB);     // 81..97
  f16*   vtb  = (f16*)(ws + 97 * MB);     // 97..113
  float* x2   = (float*)(ws + 113 * MB);  // 113..145
  f16*   a1   = (f16*)(ws + 49 * MB);     // reuse q+k after attention
  f16*   sbuf = (f16*)(ws + 81 * MB);     // reuse v+vt after attention
  f16*   act  = (f16*)(ws + 145 * MB);    // 145..177
  (void)ws_size; (void)n_in; (void)in_sizes; (void)out_size;

  const dim3 blk(256);
  const float qscale = 0.08838834764831845f;  // 1/sqrt(128)

  rope_tab_k<<<2048, 128, 0, stream>>>(Dt);
  rmsnorm_k<<<4096, blk, 0, stream>>>(x, g, hbuf);

  // Q
  convT_k<<<dim3(64, 64), blk, 0, stream>>>(wq, wT, 2048, 2048);
  gemm_k<0><<<dim3(16, 32), blk, 0, stream>>>(hbuf, wT, qbuf, 4096, 2048, 2048,
                                              nullptr, Dt, nullptr, nullptr, qscale);
  // K
  convT_k<<<dim3(64, 64), blk, 0, stream>>>(wk, wT, 2048, 2048);
  gemm_k<0><<<dim3(16, 32), blk, 0, stream>>>(hbuf, wT, kbuf, 4096, 2048, 2048,
                                              nullptr, Dt, nullptr, nullptr, 1.0f);
  // V
  convT_k<<<dim3(64, 64), blk, 0, stream>>>(wv, wT, 2048, 2048);
  gemm_k<1><<<dim3(16, 32), blk, 0, stream>>>(hbuf, wT, vbuf, 4096, 2048, 2048,
                                              nullptr, nullptr, nullptr, nullptr, 1.0f);
  vtrans_k<<<dim3(64, 4, 32), blk, 0, stream>>>(vbuf, vtb);

  attn_k<<<dim3(16, 32), blk, 0, stream>>>(qbuf, kbuf, vtb, x, x2);

  rmsnorm_k<<<4096, blk, 0, stream>>>(x2, g, hbuf);

  // a1 = h2 @ w1 + b1
  convT_k<<<dim3(128, 64), blk, 0, stream>>>(w1, wT, 2048, 4096);
  gemm_k<2><<<dim3(32, 32), blk, 0, stream>>>(hbuf, wT, a1, 4096, 4096, 2048,
                                              b1, nullptr, nullptr, nullptr, 1.0f);
  // s = silu(beta * (a1 @ wg + bg))
  convT_k<<<dim3(128, 128), blk, 0, stream>>>(wgp, wT, 4096, 4096);
  gemm_k<3><<<dim3(32, 32), blk, 0, stream>>>(a1, wT, sbuf, 4096, 4096, 4096,
                                              bg, nullptr, nullptr, beta, 1.0f);
  // act = s * (a1 @ wl + bl)
  convT_k<<<dim3(128, 128), blk, 0, stream>>>(wl, wT, 4096, 4096);
  gemm_k<4><<<dim3(32, 32), blk, 0, stream>>>(a1, wT, act, 4096, 4096, 4096,
                                              bl, nullptr, sbuf, nullptr, 1.0f);
  // out = act @ w2 + b2 + x2
  convT_k<<<dim3(64, 128), blk, 0, stream>>>(w2, wT, 4096, 2048);
  gemm_k<5><<<dim3(16, 32), blk, 0, stream>>>(act, wT, (float*)d_out, 4096, 2048, 4096,
                                              b2, x2, nullptr, nullptr, 1.0f);
}